// Round 3
// baseline (834.306 us; speedup 1.0000x reference)
//
#include <hip/hip_runtime.h>
#include <math.h>

#define C 64
#define BN 128              // nodes per destination bucket
#define BSHIFT 7            // log2(BN)
#define NPART 256           // partition blocks

__device__ __forceinline__ float sigf(float x) { return 1.0f / (1.0f + __expf(-x)); }

// ---- Kernel 1: W = max(lstm_fwd(conv_w), lstm_bwd(conv_w)) ----------------
__global__ __launch_bounds__(256) void lstm_w_kernel(
    const float* __restrict__ cw,
    const float* __restrict__ wf, const float* __restrict__ bif, const float* __restrict__ bhf,
    const float* __restrict__ wb, const float* __restrict__ bib, const float* __restrict__ bhb,
    float* __restrict__ W)
{
    int tid = blockIdx.x * blockDim.x + threadIdx.x;   // 0..4095
    int r = tid >> 6, c = tid & 63;
    const float* x = cw + r * C;

    const float* f_i = wf + (0 * C + c) * C;
    const float* f_g = wf + (2 * C + c) * C;
    const float* f_o = wf + (3 * C + c) * C;
    const float* b_i = wb + (0 * C + c) * C;
    const float* b_g = wb + (2 * C + c) * C;
    const float* b_o = wb + (3 * C + c) * C;

    float zif = 0.f, zgf = 0.f, zof = 0.f, zib = 0.f, zgb = 0.f, zob = 0.f;
    #pragma unroll
    for (int k = 0; k < C; ++k) {
        float xv = x[k];
        zif = fmaf(xv, f_i[k], zif);
        zgf = fmaf(xv, f_g[k], zgf);
        zof = fmaf(xv, f_o[k], zof);
        zib = fmaf(xv, b_i[k], zib);
        zgb = fmaf(xv, b_g[k], zgb);
        zob = fmaf(xv, b_o[k], zob);
    }
    zif += bif[0 * C + c] + bhf[0 * C + c];
    zgf += bif[2 * C + c] + bhf[2 * C + c];
    zof += bif[3 * C + c] + bhf[3 * C + c];
    zib += bib[0 * C + c] + bhb[0 * C + c];
    zgb += bib[2 * C + c] + bhb[2 * C + c];
    zob += bib[3 * C + c] + bhb[3 * C + c];

    float cf = sigf(zif) * tanhf(zgf);
    float hf = sigf(zof) * tanhf(cf);
    float cb = sigf(zib) * tanhf(zgb);
    float hb = sigf(zob) * tanhf(cb);
    W[tid] = fmaxf(hf, hb);
}

// ---- Kernel 2: per-block bucket histogram (LDS atomics only) --------------
__global__ __launch_bounds__(256) void hist_kernel(
    const int* __restrict__ col, int* __restrict__ hist,
    int E, int nbuck, int epb)
{
    __shared__ int h[1024];
    int t = threadIdx.x, b = blockIdx.x;
    for (int i = t; i < nbuck; i += 256) h[i] = 0;
    __syncthreads();
    int base = b * epb;
    int end = min(base + epb, E);
    for (int e = base + t; e < end; e += 256)
        atomicAdd(&h[col[e] >> BSHIFT], 1);
    __syncthreads();
    for (int i = t; i < nbuck; i += 256) hist[b * nbuck + i] = h[i];
}

// ---- Kernel 3: per-bucket exclusive scan over blocks (in place) -----------
// hist[b][k] becomes block b's relative cursor for bucket k; bb[k] = total.
__global__ __launch_bounds__(256) void scan_blocks_kernel(
    int* __restrict__ hist, int* __restrict__ bb, int nbuck)
{
    int k = blockIdx.x * 256 + threadIdx.x;
    if (k >= nbuck) return;
    int run = 0;
    for (int b = 0; b < NPART; ++b) {
        int v = hist[b * nbuck + k];
        hist[b * nbuck + k] = run;
        run += v;
    }
    bb[k] = run;
}

// ---- Kernel 4: exclusive scan of bucket totals (single block) -------------
__global__ __launch_bounds__(256) void scan_spine_kernel(
    int* __restrict__ bb, int nbuck, int E)
{
    __shared__ int wsum[4];
    int t = threadIdx.x;
    int base = t * 4;
    int v[4];
    #pragma unroll
    for (int j = 0; j < 4; ++j) {
        int idx = base + j;
        v[j] = (idx < nbuck) ? bb[idx] : 0;
    }
    int tsum = v[0] + v[1] + v[2] + v[3];
    int lane = t & 63, wid = t >> 6;
    int x = tsum;
    #pragma unroll
    for (int d = 1; d < 64; d <<= 1) {
        int y = __shfl_up(x, d, 64);
        if (lane >= d) x += y;
    }
    if (lane == 63) wsum[wid] = x;
    __syncthreads();
    if (t == 0) {
        int run = 0;
        #pragma unroll
        for (int w = 0; w < 4; ++w) { int z = wsum[w]; wsum[w] = run; run += z; }
    }
    __syncthreads();
    int run = x - tsum + wsum[wid];
    #pragma unroll
    for (int j = 0; j < 4; ++j) {
        int idx = base + j;
        if (idx < nbuck) bb[idx] = run;
        run += v[j];
    }
    if (t == 0) bb[nbuck] = E;
}

// ---- Kernel 5: partition — scatter {row|ld<<20, w} into bucket slots ------
__global__ __launch_bounds__(256) void partition_kernel(
    const int* __restrict__ row, const int* __restrict__ col,
    const float* __restrict__ ew, const int* __restrict__ hist,
    const int* __restrict__ bb, int2* __restrict__ payload,
    int E, int nbuck, int epb)
{
    __shared__ int cur[1024];
    int t = threadIdx.x, b = blockIdx.x;
    for (int i = t; i < nbuck; i += 256)
        cur[i] = hist[b * nbuck + i] + bb[i];
    __syncthreads();
    int base = b * epb;
    int end = min(base + epb, E);
    for (int e = base + t; e < end; e += 256) {
        int c = col[e];
        int k = c >> BSHIFT;
        int pos = atomicAdd(&cur[k], 1);
        payload[pos] = make_int2(row[e] | ((c & (BN - 1)) << 20),
                                 __float_as_int(ew[e]));
    }
}

// ---- Kernel 6: per-bucket weighted degree → dinv (LDS atomics) ------------
__global__ __launch_bounds__(256) void deg_dinv_kernel(
    const int2* __restrict__ payload, const int* __restrict__ bb,
    float* __restrict__ dinv, int N)
{
    __shared__ float degl[BN];
    int t = threadIdx.x, k = blockIdx.x;
    if (t < BN) degl[t] = 0.f;
    __syncthreads();
    int e0 = bb[k], e1 = bb[k + 1];
    for (int e = e0 + t; e < e1; e += 256) {
        int2 p = payload[e];
        atomicAdd(&degl[p.x >> 20], __int_as_float(p.y));
    }
    __syncthreads();
    int n = k * BN + t;
    if (t < BN && n < N) dinv[n] = rsqrtf(degl[t] + 1.0f);   // +1 self-loop
}

// ---- Kernel 7: Xw = X @ W  (32 rows/block, W staged once) -----------------
__global__ __launch_bounds__(256) void gemm_xw_kernel(
    const float* __restrict__ X, const float* __restrict__ W,
    float* __restrict__ Y, int N)
{
    __shared__ float Wl[C * C];
    __shared__ float xl[32][C];
    int t = threadIdx.x;
    #pragma unroll
    for (int i = 0; i < 4; ++i)
        *(float4*)(Wl + 4 * (t + i * 256)) = *(const float4*)(W + 4 * (t + i * 256));

    int n0 = blockIdx.x * 32;
    #pragma unroll
    for (int i = 0; i < 2; ++i) {
        int idx = t + i * 256;            // 0..511 : (row, float4-group)
        int rr = idx >> 4, cc = (idx & 15) << 2;
        int n = n0 + rr;
        float4 v = (n < N) ? *(const float4*)(X + (size_t)n * C + cc)
                           : make_float4(0.f, 0.f, 0.f, 0.f);
        *(float4*)(&xl[rr][cc]) = v;
    }
    __syncthreads();

    int c = t & 63, rb = (t >> 6) * 8;
    float acc[8] = {0.f, 0.f, 0.f, 0.f, 0.f, 0.f, 0.f, 0.f};
    for (int k = 0; k < C; ++k) {
        float w = Wl[k * C + c];
        #pragma unroll
        for (int q = 0; q < 8; ++q) acc[q] = fmaf(xl[rb + q][k], w, acc[q]);
    }
    #pragma unroll
    for (int q = 0; q < 8; ++q) {
        int n = n0 + rb + q;
        if (n < N) Y[(size_t)n * C + c] = acc[q];
    }
}

// ---- Kernel 8: per-bucket gather-reduce into LDS tile + fused epilogue ----
// tmp[n] = ne[n] + ce[n] + dinv[n]^2*Xw[n] + sum_e norm_e * Xw[row_e]
__global__ __launch_bounds__(512) void gather_reduce_kernel(
    const int2* __restrict__ payload, const int* __restrict__ bb,
    const float* __restrict__ Xw, const float* __restrict__ dinv,
    const float* __restrict__ ne, const float* __restrict__ ce,
    float* __restrict__ tmp, int N)
{
    __shared__ __align__(16) float acc[BN * C];   // 32 KB
    __shared__ float dl[BN];
    int t = threadIdx.x, k = blockIdx.x;

    #pragma unroll
    for (int i = 0; i < (BN * C) / (4 * 512); ++i)
        *(float4*)&acc[4 * (t + i * 512)] = make_float4(0.f, 0.f, 0.f, 0.f);
    if (t < BN) {
        int n = k * BN + t;
        dl[t] = (n < N) ? dinv[n] : 0.f;
    }
    __syncthreads();

    int e0 = bb[k], e1 = bb[k + 1];
    int w = t >> 6, l = t & 63;
    for (int e = e0 + w; e < e1; e += 8) {
        int2 p = payload[e];                       // broadcast (same addr/wave)
        int r = p.x & ((1 << 20) - 1);
        int ld = p.x >> 20;
        float norm = dinv[r] * dl[ld] * __int_as_float(p.y);
        float v = Xw[(size_t)r * C + l];           // 256B coalesced per wave
        atomicAdd(&acc[ld * C + l], norm * v);     // ds_add, 2 lanes/bank: free
    }
    __syncthreads();

    for (int f = t; f < (BN * C) / 4; f += 512) {
        int ld = f >> 4, g = (f & 15) << 2;
        int n = k * BN + ld;
        if (n >= N) continue;
        float di = dl[ld], d2 = di * di;
        size_t o = (size_t)n * C + g;
        float4 a = *(float4*)&acc[ld * C + g];
        const float4 xv = *(const float4*)(Xw + o);
        const float4 nv = *(const float4*)(ne + o);
        const float4 cv = *(const float4*)(ce + o);
        a.x += nv.x + cv.x + xv.x * d2;
        a.y += nv.y + cv.y + xv.y * d2;
        a.z += nv.z + cv.z + xv.z * d2;
        a.w += nv.w + cv.w + xv.w * d2;
        *(float4*)(tmp + o) = a;
    }
}

// ---- Kernel 9: out = tmp @ fW^T + fb  (32 rows/block) ---------------------
__global__ __launch_bounds__(256) void fusion_kernel(
    const float* __restrict__ tmp, const float* __restrict__ fW,
    const float* __restrict__ fb, float* __restrict__ out, int N)
{
    __shared__ float Wt[C][C + 1];   // Wt[k][j] = fW[j*C+k]
    __shared__ float tl[32][C];
    int t = threadIdx.x;
    #pragma unroll
    for (int i = 0; i < 16; ++i) {
        int idx = t + i * 256;
        Wt[idx & 63][idx >> 6] = fW[idx];
    }
    int n0 = blockIdx.x * 32;
    #pragma unroll
    for (int i = 0; i < 2; ++i) {
        int idx = t + i * 256;
        int rr = idx >> 4, cc = (idx & 15) << 2;
        int n = n0 + rr;
        float4 v = (n < N) ? *(const float4*)(tmp + (size_t)n * C + cc)
                           : make_float4(0.f, 0.f, 0.f, 0.f);
        *(float4*)(&tl[rr][cc]) = v;
    }
    __syncthreads();

    int j = t & 63, rb = (t >> 6) * 8;
    float bj = fb[j];
    float acc[8] = {bj, bj, bj, bj, bj, bj, bj, bj};
    for (int k = 0; k < C; ++k) {
        float w = Wt[k][j];
        #pragma unroll
        for (int q = 0; q < 8; ++q) acc[q] = fmaf(tl[rb + q][k], w, acc[q]);
    }
    #pragma unroll
    for (int q = 0; q < 8; ++q) {
        int n = n0 + rb + q;
        if (n < N) out[(size_t)n * C + j] = acc[q];
    }
}

extern "C" void kernel_launch(void* const* d_in, const int* in_sizes, int n_in,
                              void* d_out, int out_size, void* d_ws, size_t ws_size,
                              hipStream_t stream)
{
    const float* X        = (const float*)d_in[0];
    const int*   ei       = (const int*)d_in[1];
    const float* ew       = (const float*)d_in[2];
    const float* node_emb = (const float*)d_in[3];
    const float* com_emb  = (const float*)d_in[4];
    const float* cw       = (const float*)d_in[5];
    const float* w_ih_f   = (const float*)d_in[6];
    const float* b_ih_f   = (const float*)d_in[7];
    const float* b_hh_f   = (const float*)d_in[8];
    const float* w_ih_b   = (const float*)d_in[9];
    const float* b_ih_b   = (const float*)d_in[10];
    const float* b_hh_b   = (const float*)d_in[11];
    const float* fW       = (const float*)d_in[12];
    const float* fb       = (const float*)d_in[13];
    float* out = (float*)d_out;

    const int N = in_sizes[0] / C;
    const int E = in_sizes[2];
    const int* row = ei;               // edge_index[0]
    const int* col = ei + E;           // edge_index[1]
    const int nbuck = (N + BN - 1) / BN;
    const int epb = (E + NPART - 1) / NPART;

    // ---- workspace layout ----
    char* wsb = (char*)d_ws;
    size_t o = 0;
    auto alloc = [&](size_t bytes) { void* p = wsb + o; o = (o + bytes + 15) & ~(size_t)15; return p; };
    float* W       = (float*)alloc((size_t)C * C * sizeof(float));     // 16 KB
    float* dinv    = (float*)alloc((size_t)N * sizeof(float));         // 400 KB
    int*   bb      = (int*)  alloc((size_t)(nbuck + 1) * sizeof(int)); // 3 KB
    int2*  payload = (int2*) alloc((size_t)E * sizeof(int2));          // 12.8 MB
    float* tmp     = (float*)alloc((size_t)N * C * sizeof(float));     // 25.6 MB
    int*   hist    = (int*)tmp;        // alias: dead before tmp is written
    float* Xw      = out;              // d_out holds Xw until fusion overwrites

    lstm_w_kernel<<<(C * C) / 256, 256, 0, stream>>>(
        cw, w_ih_f, b_ih_f, b_hh_f, w_ih_b, b_ih_b, b_hh_b, W);

    hist_kernel<<<NPART, 256, 0, stream>>>(col, hist, E, nbuck, epb);
    scan_blocks_kernel<<<(nbuck + 255) / 256, 256, 0, stream>>>(hist, bb, nbuck);
    scan_spine_kernel<<<1, 256, 0, stream>>>(bb, nbuck, E);
    partition_kernel<<<NPART, 256, 0, stream>>>(
        row, col, ew, hist, bb, payload, E, nbuck, epb);

    deg_dinv_kernel<<<nbuck, 256, 0, stream>>>(payload, bb, dinv, N);

    gemm_xw_kernel<<<(N + 31) / 32, 256, 0, stream>>>(X, W, Xw, N);

    gather_reduce_kernel<<<nbuck, 512, 0, stream>>>(
        payload, bb, Xw, dinv, node_emb, com_emb, tmp, N);

    fusion_kernel<<<(N + 31) / 32, 256, 0, stream>>>(tmp, fW, fb, out, N);
}

// Round 4
// 231.068 us; speedup vs baseline: 3.6106x; 3.6106x over previous
//
#include <hip/hip_runtime.h>
#include <math.h>

#define C 64
#define BN 128              // nodes per destination bucket
#define BSHIFT 7            // log2(BN)
#define NPART 256           // partition blocks
#define RMASK ((1 << 20) - 1)

__device__ __forceinline__ float sigf(float x) { return 1.0f / (1.0f + __expf(-x)); }

// ---- Kernel 1: W = max(lstm_fwd(conv_w), lstm_bwd(conv_w)) ----------------
__global__ __launch_bounds__(256) void lstm_w_kernel(
    const float* __restrict__ cw,
    const float* __restrict__ wf, const float* __restrict__ bif, const float* __restrict__ bhf,
    const float* __restrict__ wb, const float* __restrict__ bib, const float* __restrict__ bhb,
    float* __restrict__ W)
{
    int tid = blockIdx.x * blockDim.x + threadIdx.x;   // 0..4095
    int r = tid >> 6, c = tid & 63;
    const float* x = cw + r * C;

    const float* f_i = wf + (0 * C + c) * C;
    const float* f_g = wf + (2 * C + c) * C;
    const float* f_o = wf + (3 * C + c) * C;
    const float* b_i = wb + (0 * C + c) * C;
    const float* b_g = wb + (2 * C + c) * C;
    const float* b_o = wb + (3 * C + c) * C;

    float zif = 0.f, zgf = 0.f, zof = 0.f, zib = 0.f, zgb = 0.f, zob = 0.f;
    #pragma unroll
    for (int k = 0; k < C; ++k) {
        float xv = x[k];
        zif = fmaf(xv, f_i[k], zif);
        zgf = fmaf(xv, f_g[k], zgf);
        zof = fmaf(xv, f_o[k], zof);
        zib = fmaf(xv, b_i[k], zib);
        zgb = fmaf(xv, b_g[k], zgb);
        zob = fmaf(xv, b_o[k], zob);
    }
    zif += bif[0 * C + c] + bhf[0 * C + c];
    zgf += bif[2 * C + c] + bhf[2 * C + c];
    zof += bif[3 * C + c] + bhf[3 * C + c];
    zib += bib[0 * C + c] + bhb[0 * C + c];
    zgb += bib[2 * C + c] + bhb[2 * C + c];
    zob += bib[3 * C + c] + bhb[3 * C + c];

    float cf = sigf(zif) * tanhf(zgf);
    float hf = sigf(zof) * tanhf(cf);
    float cb = sigf(zib) * tanhf(zgb);
    float hb = sigf(zob) * tanhf(cb);
    W[tid] = fmaxf(hf, hb);
}

// ---- Kernel 2: per-block bucket histogram (LDS atomics only) --------------
__global__ __launch_bounds__(256) void hist_kernel(
    const int* __restrict__ col, int* __restrict__ hist,
    int E, int nbuck, int epb)
{
    __shared__ int h[1024];
    int t = threadIdx.x, b = blockIdx.x;
    for (int i = t; i < nbuck; i += 256) h[i] = 0;
    __syncthreads();
    int base = b * epb;
    int end = min(base + epb, E);
    for (int e = base + t; e < end; e += 256)
        atomicAdd(&h[col[e] >> BSHIFT], 1);
    __syncthreads();
    for (int i = t; i < nbuck; i += 256) hist[b * nbuck + i] = h[i];
}

// ---- Kernel 3: per-bucket exclusive scan over blocks (in place) -----------
__global__ __launch_bounds__(256) void scan_blocks_kernel(
    int* __restrict__ hist, int* __restrict__ bb, int nbuck)
{
    int k = blockIdx.x * 256 + threadIdx.x;
    if (k >= nbuck) return;
    int run = 0;
    for (int b = 0; b < NPART; ++b) {
        int v = hist[b * nbuck + k];
        hist[b * nbuck + k] = run;
        run += v;
    }
    bb[k] = run;
}

// ---- Kernel 4: exclusive scan of bucket totals (single block) -------------
__global__ __launch_bounds__(256) void scan_spine_kernel(
    int* __restrict__ bb, int nbuck, int E)
{
    __shared__ int wsum[4];
    int t = threadIdx.x;
    int base = t * 4;
    int v[4];
    #pragma unroll
    for (int j = 0; j < 4; ++j) {
        int idx = base + j;
        v[j] = (idx < nbuck) ? bb[idx] : 0;
    }
    int tsum = v[0] + v[1] + v[2] + v[3];
    int lane = t & 63, wid = t >> 6;
    int x = tsum;
    #pragma unroll
    for (int d = 1; d < 64; d <<= 1) {
        int y = __shfl_up(x, d, 64);
        if (lane >= d) x += y;
    }
    if (lane == 63) wsum[wid] = x;
    __syncthreads();
    if (t == 0) {
        int run = 0;
        #pragma unroll
        for (int w = 0; w < 4; ++w) { int z = wsum[w]; wsum[w] = run; run += z; }
    }
    __syncthreads();
    int run = x - tsum + wsum[wid];
    #pragma unroll
    for (int j = 0; j < 4; ++j) {
        int idx = base + j;
        if (idx < nbuck) bb[idx] = run;
        run += v[j];
    }
    if (t == 0) bb[nbuck] = E;
}

// ---- Kernel 5: partition — scatter {row|ld<<20, w} into bucket ranges -----
__global__ __launch_bounds__(256) void partition_kernel(
    const int* __restrict__ row, const int* __restrict__ col,
    const float* __restrict__ ew, const int* __restrict__ hist,
    const int* __restrict__ bb, int2* __restrict__ payload,
    int E, int nbuck, int epb)
{
    __shared__ int cur[1024];
    int t = threadIdx.x, b = blockIdx.x;
    for (int i = t; i < nbuck; i += 256)
        cur[i] = hist[b * nbuck + i] + bb[i];
    __syncthreads();
    int base = b * epb;
    int end = min(base + epb, E);
    for (int e = base + t; e < end; e += 256) {
        int c = col[e];
        int k = c >> BSHIFT;
        int pos = atomicAdd(&cur[k], 1);
        payload[pos] = make_int2(row[e] | ((c & (BN - 1)) << 20),
                                 __float_as_int(ew[e]));
    }
}

// ---- Kernel 6: per-bucket counting sort by node + deg/dinv + fold dinv[dst]
// In:  payload {row|ld<<20, w} grouped by bucket.
// Out: payload2 {row, w*dinv[dst]} sorted by dst node; seg[n]={start,count};
//      dinv[n] global.
__global__ __launch_bounds__(256) void sort_bucket_kernel(
    const int2* __restrict__ payload, const int* __restrict__ bb,
    int2* __restrict__ payload2, float* __restrict__ dinv,
    int2* __restrict__ seg, int N)
{
    __shared__ int bin[BN];
    __shared__ int bbase[BN];
    __shared__ int cur[BN];
    __shared__ float degl[BN];
    __shared__ float dinvl[BN];
    int t = threadIdx.x, k = blockIdx.x;
    if (t < BN) { bin[t] = 0; degl[t] = 0.f; }
    __syncthreads();

    int e0 = bb[k], e1 = bb[k + 1];
    for (int e = e0 + t; e < e1; e += 256) {
        int2 p = payload[e];
        int ld = p.x >> 20;
        atomicAdd(&bin[ld], 1);
        atomicAdd(&degl[ld], __int_as_float(p.y));
    }
    __syncthreads();

    // exclusive scan of bin[0..127] in wave 0 (2 bins per lane)
    if (t < 64) {
        int a = bin[2 * t], b2 = bin[2 * t + 1];
        int s = a + b2;
        int x = s;
        #pragma unroll
        for (int d = 1; d < 64; d <<= 1) {
            int y = __shfl_up(x, d, 64);
            if (t >= d) x += y;
        }
        int excl = x - s;
        bbase[2 * t] = excl;
        bbase[2 * t + 1] = excl + a;
    }
    __syncthreads();

    if (t < BN) {
        int n = k * BN + t;
        float di = rsqrtf(degl[t] + 1.0f);    // +1 self-loop weight
        dinvl[t] = di;
        cur[t] = e0 + bbase[t];
        if (n < N) {
            dinv[n] = di;
            seg[n] = make_int2(e0 + bbase[t], bin[t]);
        }
    }
    __syncthreads();

    for (int e = e0 + t; e < e1; e += 256) {
        int2 p = payload[e];
        int ld = p.x >> 20;
        int pos = atomicAdd(&cur[ld], 1);
        payload2[pos] = make_int2(p.x & RMASK,
                                  __float_as_int(__int_as_float(p.y) * dinvl[ld]));
    }
}

// ---- Kernel 7: Xw = X @ W  (32 rows/block, W staged once) -----------------
__global__ __launch_bounds__(256) void gemm_xw_kernel(
    const float* __restrict__ X, const float* __restrict__ W,
    float* __restrict__ Y, int N)
{
    __shared__ float Wl[C * C];
    __shared__ float xl[32][C];
    int t = threadIdx.x;
    #pragma unroll
    for (int i = 0; i < 4; ++i)
        *(float4*)(Wl + 4 * (t + i * 256)) = *(const float4*)(W + 4 * (t + i * 256));

    int n0 = blockIdx.x * 32;
    #pragma unroll
    for (int i = 0; i < 2; ++i) {
        int idx = t + i * 256;            // 0..511 : (row, float4-group)
        int rr = idx >> 4, cc = (idx & 15) << 2;
        int n = n0 + rr;
        float4 v = (n < N) ? *(const float4*)(X + (size_t)n * C + cc)
                           : make_float4(0.f, 0.f, 0.f, 0.f);
        *(float4*)(&xl[rr][cc]) = v;
    }
    __syncthreads();

    int c = t & 63, rb = (t >> 6) * 8;
    float acc[8] = {0.f, 0.f, 0.f, 0.f, 0.f, 0.f, 0.f, 0.f};
    for (int k = 0; k < C; ++k) {
        float w = Wl[k * C + c];
        #pragma unroll
        for (int q = 0; q < 8; ++q) acc[q] = fmaf(xl[rb + q][k], w, acc[q]);
    }
    #pragma unroll
    for (int q = 0; q < 8; ++q) {
        int n = n0 + rb + q;
        if (n < N) Y[(size_t)n * C + c] = acc[q];
    }
}

// ---- Kernel 8: gather-reduce, 16 lanes/node, no atomics -------------------
// tmp[n] = ne[n] + ce[n] + dinv[n]^2*Xw[n] + sum_seg (dinv[row]*pn) * Xw[row]
__global__ __launch_bounds__(256) void reduce_kernel(
    const int2* __restrict__ seg, const int2* __restrict__ payload2,
    const float* __restrict__ Xw, const float* __restrict__ dinv,
    const float* __restrict__ ne, const float* __restrict__ ce,
    float* __restrict__ tmp, int N)
{
    int t = blockIdx.x * 256 + threadIdx.x;
    int n = t >> 4;
    if (n >= N) return;
    int g = (t & 15) << 2;

    int2 s = seg[n];
    int pend = s.x + s.y;
    float4 acc = make_float4(0.f, 0.f, 0.f, 0.f);
    for (int p = s.x; p < pend; ++p) {
        int2 pl = payload2[p];                       // 8B broadcast in group
        float norm = dinv[pl.x] * __int_as_float(pl.y);
        const float4 v = *(const float4*)(Xw + (size_t)pl.x * C + g);
        acc.x = fmaf(v.x, norm, acc.x);
        acc.y = fmaf(v.y, norm, acc.y);
        acc.z = fmaf(v.z, norm, acc.z);
        acc.w = fmaf(v.w, norm, acc.w);
    }
    float di = dinv[n], d2 = di * di;
    size_t o = (size_t)n * C + g;
    const float4 xv = *(const float4*)(Xw + o);
    const float4 nv = *(const float4*)(ne + o);
    const float4 cv = *(const float4*)(ce + o);
    acc.x += nv.x + cv.x + xv.x * d2;
    acc.y += nv.y + cv.y + xv.y * d2;
    acc.z += nv.z + cv.z + xv.z * d2;
    acc.w += nv.w + cv.w + xv.w * d2;
    *(float4*)(tmp + o) = acc;
}

// ---- Kernel 9: out = tmp @ fW^T + fb  (32 rows/block) ---------------------
__global__ __launch_bounds__(256) void fusion_kernel(
    const float* __restrict__ tmp, const float* __restrict__ fW,
    const float* __restrict__ fb, float* __restrict__ out, int N)
{
    __shared__ float Wt[C][C + 1];   // Wt[k][j] = fW[j*C+k]
    __shared__ float tl[32][C];
    int t = threadIdx.x;
    #pragma unroll
    for (int i = 0; i < 16; ++i) {
        int idx = t + i * 256;
        Wt[idx & 63][idx >> 6] = fW[idx];
    }
    int n0 = blockIdx.x * 32;
    #pragma unroll
    for (int i = 0; i < 2; ++i) {
        int idx = t + i * 256;
        int rr = idx >> 4, cc = (idx & 15) << 2;
        int n = n0 + rr;
        float4 v = (n < N) ? *(const float4*)(tmp + (size_t)n * C + cc)
                           : make_float4(0.f, 0.f, 0.f, 0.f);
        *(float4*)(&tl[rr][cc]) = v;
    }
    __syncthreads();

    int j = t & 63, rb = (t >> 6) * 8;
    float bj = fb[j];
    float acc[8] = {bj, bj, bj, bj, bj, bj, bj, bj};
    for (int k = 0; k < C; ++k) {
        float w = Wt[k][j];
        #pragma unroll
        for (int q = 0; q < 8; ++q) acc[q] = fmaf(tl[rb + q][k], w, acc[q]);
    }
    #pragma unroll
    for (int q = 0; q < 8; ++q) {
        int n = n0 + rb + q;
        if (n < N) out[(size_t)n * C + j] = acc[q];
    }
}

extern "C" void kernel_launch(void* const* d_in, const int* in_sizes, int n_in,
                              void* d_out, int out_size, void* d_ws, size_t ws_size,
                              hipStream_t stream)
{
    const float* X        = (const float*)d_in[0];
    const int*   ei       = (const int*)d_in[1];
    const float* ew       = (const float*)d_in[2];
    const float* node_emb = (const float*)d_in[3];
    const float* com_emb  = (const float*)d_in[4];
    const float* cw       = (const float*)d_in[5];
    const float* w_ih_f   = (const float*)d_in[6];
    const float* b_ih_f   = (const float*)d_in[7];
    const float* b_hh_f   = (const float*)d_in[8];
    const float* w_ih_b   = (const float*)d_in[9];
    const float* b_ih_b   = (const float*)d_in[10];
    const float* b_hh_b   = (const float*)d_in[11];
    const float* fW       = (const float*)d_in[12];
    const float* fb       = (const float*)d_in[13];
    float* out = (float*)d_out;

    const int N = in_sizes[0] / C;
    const int E = in_sizes[2];
    const int* row = ei;               // edge_index[0]
    const int* col = ei + E;           // edge_index[1]
    const int nbuck = (N + BN - 1) / BN;
    const int epb = (E + NPART - 1) / NPART;

    // ---- workspace layout ----
    // [W][dinv][bb][seg][payload2: E*8][tmp: N*C*4]
    // pass-1 payload + hist alias INTO the tmp region (dead before reduce).
    char* wsb = (char*)d_ws;
    size_t o = 0;
    auto alloc = [&](size_t bytes) { void* p = wsb + o; o = (o + bytes + 15) & ~(size_t)15; return p; };
    float* W        = (float*)alloc((size_t)C * C * sizeof(float));      // 16 KB
    float* dinv     = (float*)alloc((size_t)N * sizeof(float));          // 400 KB
    int*   bb       = (int*)  alloc((size_t)(nbuck + 1) * sizeof(int));  // 3 KB
    int2*  seg      = (int2*) alloc((size_t)N * sizeof(int2));           // 800 KB
    int2*  payload2 = (int2*) alloc((size_t)E * sizeof(int2));           // 12.8 MB
    float* tmp      = (float*)alloc((size_t)N * C * sizeof(float));      // 25.6 MB
    int2*  payload  = (int2*)tmp;                       // 12.8 MB alias
    int*   hist     = (int*)(tmp + (size_t)E * 2);      // 800 KB alias after payload

    lstm_w_kernel<<<(C * C) / 256, 256, 0, stream>>>(
        cw, w_ih_f, b_ih_f, b_hh_f, w_ih_b, b_ih_b, b_hh_b, W);

    hist_kernel<<<NPART, 256, 0, stream>>>(col, hist, E, nbuck, epb);
    scan_blocks_kernel<<<(nbuck + 255) / 256, 256, 0, stream>>>(hist, bb, nbuck);
    scan_spine_kernel<<<1, 256, 0, stream>>>(bb, nbuck, E);
    partition_kernel<<<NPART, 256, 0, stream>>>(
        row, col, ew, hist, bb, payload, E, nbuck, epb);

    sort_bucket_kernel<<<nbuck, 256, 0, stream>>>(
        payload, bb, payload2, dinv, seg, N);

    gemm_xw_kernel<<<(N + 31) / 32, 256, 0, stream>>>(X, W, out, N);

    reduce_kernel<<<(N * 16 + 255) / 256, 256, 0, stream>>>(
        seg, payload2, out, dinv, node_emb, com_emb, tmp, N);

    fusion_kernel<<<(N + 31) / 32, 256, 0, stream>>>(tmp, fW, fb, out, N);
}